// Round 13
// baseline (622.146 us; speedup 1.0000x reference)
//
#include <hip/hip_runtime.h>

#define N_NODES 50000
#define N_GRAPHS 500
#define N_EDGES 800000
#define BUCK_SHIFT 7
#define NBUCK 391   // cdiv(N_NODES, 128)
#define EPB_A 8192  // edges per bin block (32/thread)

static inline int cdiv(int a, int b) { return (a + b - 1) / b; }

typedef _Float16 half8v __attribute__((ext_vector_type(8)));
typedef _Float16 half4v __attribute__((ext_vector_type(4)));
typedef __attribute__((ext_vector_type(4))) float f32x4;

__device__ __forceinline__ _Float16 f2h(float f) { return (_Float16)f; }

// ---------------- CSR build ----------------

__global__ void count_kernel(const int* __restrict__ row, int* __restrict__ cnt, int e) {
    int t = blockIdx.x * blockDim.x + threadIdx.x;
    if (t < e) atomicAdd(&cnt[row[t]], 1);
}

__global__ void block_scan_kernel(const int* __restrict__ cnt, int* __restrict__ rp,
                                  int* __restrict__ bsum, int n) {
    __shared__ int buf[2][256];
    int t = threadIdx.x;
    int idx = blockIdx.x * 256 + t;
    int v = (idx < n) ? cnt[idx] : 0;
    buf[0][t] = v;
    __syncthreads();
    int s = 0;
#pragma unroll
    for (int off = 1; off < 256; off <<= 1) {
        int x = buf[s][t];
        if (t >= off) x += buf[s][t - off];
        buf[s ^ 1][t] = x;
        s ^= 1;
        __syncthreads();
    }
    if (idx < n) rp[idx] = buf[s][t] - v;  // exclusive within block
    if (t == 255) bsum[blockIdx.x] = buf[s][255];
}

__global__ void scan_bsum_kernel(int* __restrict__ bsum, int nb) {
    __shared__ int buf[2][256];
    int t = threadIdx.x;
    int v = (t < nb) ? bsum[t] : 0;
    buf[0][t] = v;
    __syncthreads();
    int s = 0;
#pragma unroll
    for (int off = 1; off < 256; off <<= 1) {
        int x = buf[s][t];
        if (t >= off) x += buf[s][t - off];
        buf[s ^ 1][t] = x;
        s ^= 1;
        __syncthreads();
    }
    if (t < nb) bsum[t] = buf[s][t] - v;  // exclusive
}

__global__ void add_off_kernel(int* __restrict__ rp, const int* __restrict__ bsum, int n) {
    int idx = blockIdx.x * 256 + threadIdx.x;
    if (idx < n) rp[idx] += bsum[idx >> 8];
    if (idx == 0) rp[n] = N_EDGES;
}

// cursor copy + dinv + per-bucket global cursors (gcur[b] = rp[b*128])
__global__ void dinv_cursor_kernel(const int* __restrict__ cnt, const int* __restrict__ rp,
                                   float* __restrict__ dinv, int* __restrict__ cursor,
                                   int* __restrict__ gcur, int n) {
    int t = blockIdx.x * blockDim.x + threadIdx.x;
    if (t < n) {
        int c = cnt[t];
        dinv[t] = (c > 0) ? rsqrtf((float)c) : 0.0f;
        cursor[t] = rp[t];
    }
    if (t < NBUCK) gcur[t] = rp[t << BUCK_SHIFT];
}

// Phase A: bin edges by row>>7 into bucket-contiguous staging.
// Per (block,bucket) chunk is contiguous -> mostly full-line writes.
__global__ __launch_bounds__(256) void bin_kernel(
    const int* __restrict__ row, const int* __restrict__ col,
    const float* __restrict__ dinv, int* __restrict__ gcur,
    int2* __restrict__ stage, int e) {
    __shared__ int lhist[NBUCK];
    __shared__ int lbase[NBUCK];
    int tid = threadIdx.x;
    int base = blockIdx.x * EPB_A;
    for (int b = tid; b < NBUCK; b += 256) lhist[b] = 0;
    __syncthreads();
#pragma unroll
    for (int u = 0; u < EPB_A / 256; ++u) {
        int e_ = base + u * 256 + tid;
        if (e_ < e) atomicAdd(&lhist[row[e_] >> BUCK_SHIFT], 1);
    }
    __syncthreads();
    for (int b = tid; b < NBUCK; b += 256) {
        int c = lhist[b];
        lbase[b] = c ? atomicAdd(&gcur[b], c) : 0;
        lhist[b] = 0;
    }
    __syncthreads();
#pragma unroll
    for (int u = 0; u < EPB_A / 256; ++u) {
        int e_ = base + u * 256 + tid;
        if (e_ < e) {
            int r = row[e_], c = col[e_];
            int b = r >> BUCK_SHIFT;
            int pos = lbase[b] + atomicAdd(&lhist[b], 1);
            float w = -dinv[r] * dinv[c];
            unsigned short wb = __builtin_bit_cast(unsigned short, (_Float16)w);
            stage[pos] = make_int2(r, (int)(((unsigned)c << 16) | (unsigned)wb));
        }
    }
}

// Phase B: place within bucket (destination region ~8KB -> L2-hot).
__global__ void place_kernel(const int2* __restrict__ stage, int* __restrict__ cursor,
                             unsigned* __restrict__ ew, int e) {
    int t = blockIdx.x * blockDim.x + threadIdx.x;
    if (t < e) {
        int2 s = stage[t];
        int pos = atomicAdd(&cursor[s.x], 1);
        ew[pos] = (unsigned)s.y;
    }
}

// ---------------- fused fp16 conversions (single kernel) ----------------

__global__ void conv_all_kernel(const float* __restrict__ x, const float* __restrict__ W1,
                                const float* __restrict__ W2, const float* __restrict__ W3,
                                const float* __restrict__ W4, const float* __restrict__ W5,
                                _Float16* __restrict__ xh, _Float16* __restrict__ wt1,
                                _Float16* __restrict__ wt2, _Float16* __restrict__ wt3,
                                _Float16* __restrict__ wt4, _Float16* __restrict__ wt5) {
    int t = blockIdx.x * blockDim.x + threadIdx.x;
    const int NX = N_NODES * 128;
    if (t < NX) {
        int r = t >> 7, c = t & 127;
        xh[t] = (c < 116) ? f2h(x[(size_t)r * 116 + c]) : (_Float16)0.f;
        return;
    }
    t -= NX;
    if (t < 160 * 128) {  // wt1[c][k] = W1[c/32][k][c%32], zero-pad k>=116
        int c = t >> 7, k = t & 127;
        wt1[t] = (k < 116) ? f2h(W1[(c >> 5) * (116 * 32) + k * 32 + (c & 31)]) : (_Float16)0.f;
        return;
    }
    t -= 160 * 128;
    if (t < 32 * 160) { int c = t / 160, k = t % 160; wt2[t] = f2h(W2[(size_t)k * 32 + c]); return; }
    t -= 32 * 160;
    if (t < 64 * 160) { int c = t / 160, k = t % 160; wt3[t] = f2h(W3[(size_t)k * 64 + c]); return; }
    t -= 64 * 160;
    if (t < 64 * 320) { int c = t / 320, k = t % 320; wt4[t] = f2h(W4[(size_t)k * 64 + c]); return; }
    t -= 64 * 320;
    if (t < 128 * 320) { int c = t / 320, k = t % 320; wt5[t] = f2h(W5[(size_t)k * 128 + c]); }
}

// ---------------- fused SpMM (all-fp16, 8-deep gather MLP) ----------------

template <int F, bool HAS_A, bool HAS_B, bool RELU>
__global__ __launch_bounds__(256) void spmm_fused(
    const int* __restrict__ rp, const unsigned* __restrict__ ew,
    const _Float16* __restrict__ src, int ld_s, float alpha,
    const _Float16* __restrict__ A, int ldA, float cA,
    const _Float16* __restrict__ B, int ldB, float cB,
    const float* __restrict__ bias, _Float16* __restrict__ outh, int ldO) {
    constexpr int TPN = F / 4;
    int t = blockIdx.x * blockDim.x + threadIdx.x;
    if (t >= N_NODES * TPN) return;
    int node = t / TPN;
    int f = (t % TPN) * 4;
    const _Float16* sf = src + f;
    int e0 = rp[node], e1 = rp[node + 1];
    float ax = 0.f, ay = 0.f, az = 0.f, aw = 0.f;
    int j = e0;
    for (; j + 7 < e1; j += 8) {
        unsigned e_[8];
#pragma unroll
        for (int u = 0; u < 8; ++u) e_[u] = ew[j + u];
        half4v v_[8];
#pragma unroll
        for (int u = 0; u < 8; ++u) v_[u] = *(const half4v*)(sf + (size_t)(e_[u] >> 16) * ld_s);
#pragma unroll
        for (int u = 0; u < 8; ++u) {
            float w = (float)__builtin_bit_cast(_Float16, (unsigned short)e_[u]);
            ax += w * (float)v_[u].x;
            ay += w * (float)v_[u].y;
            az += w * (float)v_[u].z;
            aw += w * (float)v_[u].w;
        }
    }
    for (; j + 3 < e1; j += 4) {
        unsigned e_[4];
#pragma unroll
        for (int u = 0; u < 4; ++u) e_[u] = ew[j + u];
        half4v v_[4];
#pragma unroll
        for (int u = 0; u < 4; ++u) v_[u] = *(const half4v*)(sf + (size_t)(e_[u] >> 16) * ld_s);
#pragma unroll
        for (int u = 0; u < 4; ++u) {
            float w = (float)__builtin_bit_cast(_Float16, (unsigned short)e_[u]);
            ax += w * (float)v_[u].x;
            ay += w * (float)v_[u].y;
            az += w * (float)v_[u].z;
            aw += w * (float)v_[u].w;
        }
    }
    for (; j < e1; ++j) {
        unsigned ea = ew[j];
        float w0 = (float)__builtin_bit_cast(_Float16, (unsigned short)ea);
        half4v v0 = *(const half4v*)(sf + (size_t)(ea >> 16) * ld_s);
        ax += w0 * (float)v0.x;
        ay += w0 * (float)v0.y;
        az += w0 * (float)v0.z;
        aw += w0 * (float)v0.w;
    }
    float rx = alpha * ax, ry = alpha * ay, rz = alpha * az, rw = alpha * aw;
    if (HAS_A) {
        half4v a4 = *(const half4v*)(A + (size_t)node * ldA + f);
        rx += cA * (float)a4.x; ry += cA * (float)a4.y;
        rz += cA * (float)a4.z; rw += cA * (float)a4.w;
    }
    if (HAS_B) {
        half4v b4 = *(const half4v*)(B + (size_t)node * ldB + f);
        rx += cB * (float)b4.x; ry += cB * (float)b4.y;
        rz += cB * (float)b4.z; rw += cB * (float)b4.w;
    }
    if (RELU) {
        float4 bb = *(const float4*)(bias + f);
        rx = fmaxf(rx + bb.x, 0.f); ry = fmaxf(ry + bb.y, 0.f);
        rz = fmaxf(rz + bb.z, 0.f); rw = fmaxf(rw + bb.w, 0.f);
    }
    half4v h4;
    h4.x = f2h(rx); h4.y = f2h(ry); h4.z = f2h(rz); h4.w = f2h(rw);
    *(half4v*)(outh + (size_t)node * ldO + f) = h4;
}

// ---------------- MFMA matmul (fp16, W staged in LDS) ----------------
// C/D: col = lane&15, row = (lane>>4)*4 + reg  [verified layout].

template <int KB, int F0, int FOUT, bool DUAL, bool RELU>
__global__ __launch_bounds__(256) void mm_mfma(const _Float16* __restrict__ A0h,
                                               const _Float16* __restrict__ A1h,
                                               const _Float16* __restrict__ Wt,
                                               const float* __restrict__ bias,
                                               _Float16* __restrict__ outh) {
    constexpr int NT = FOUT / 16;
    constexpr int LD1 = (KB - F0) > 0 ? (KB - F0) : 1;
    constexpr int KC = (KB > 160) ? 160 : KB;
    constexpr int NCH = KB / KC;
    constexpr int LDW = KC + 8;
    __shared__ _Float16 lw[FOUT][LDW];

    int tid = threadIdx.x;
    int l = tid & 63;
    int w = tid >> 6;
    int row0 = blockIdx.x * 64 + w * 16;
    int r15 = l & 15;
    int kg = l >> 4;
    int rr = row0 + r15;
    if (rr > N_NODES - 1) rr = N_NODES - 1;  // clamp; stores are guarded

    f32x4 acc[NT];
#pragma unroll
    for (int ct = 0; ct < NT; ++ct) acc[ct] = (f32x4){0.f, 0.f, 0.f, 0.f};

#pragma unroll
    for (int ch = 0; ch < NCH; ++ch) {
        constexpr int C8 = KC / 8;
        int c0 = ch * KC;
        for (int idx = tid; idx < FOUT * C8; idx += 256) {
            int r = idx / C8, c8 = idx - r * C8;
            *(half8v*)&lw[r][c8 * 8] = *(const half8v*)(Wt + (size_t)r * KB + c0 + c8 * 8);
        }
        __syncthreads();
#pragma unroll
        for (int k0 = 0; k0 < KC; k0 += 32) {
            int gc = c0 + k0;
            int kl = gc + kg * 8;
            const _Float16* ap;
            if (!DUAL || gc < F0)
                ap = A0h + (size_t)rr * F0 + kl;
            else
                ap = A1h + (size_t)rr * LD1 + (kl - F0);
            half8v af = *(const half8v*)ap;
#pragma unroll
            for (int ct = 0; ct < NT; ++ct) {
                half8v bf = *(const half8v*)&lw[ct * 16 + r15][k0 + kg * 8];
                acc[ct] = __builtin_amdgcn_mfma_f32_16x16x32_f16(af, bf, acc[ct], 0, 0, 0);
            }
        }
        __syncthreads();
    }

    int orow = row0 + kg * 4;
#pragma unroll
    for (int ct = 0; ct < NT; ++ct) {
        int col = ct * 16 + r15;
        float bv = RELU ? bias[col] : 0.f;
#pragma unroll
        for (int i = 0; i < 4; ++i) {
            int rw = orow + i;
            if (rw < N_NODES) {
                float v = acc[ct][i];
                if (RELU) v = fmaxf(v + bv, 0.f);
                outh[(size_t)rw * FOUT + col] = f2h(v);
            }
        }
    }
}

// ---------------- pooling + linear + log_softmax (fp16 input, fp32 math) ----------------

__global__ void pool_head_kernel(const _Float16* __restrict__ h, const int* __restrict__ batch,
                                 const float* __restrict__ lw, const float* __restrict__ lb,
                                 float* __restrict__ out) {
    int g = blockIdx.x;
    int f = threadIdx.x;
    int s, e;
    {
        int lo = 0, hi = N_NODES;
        while (lo < hi) { int mid = (lo + hi) >> 1; if (batch[mid] < g) lo = mid + 1; else hi = mid; }
        s = lo;
        hi = N_NODES;
        while (lo < hi) { int mid = (lo + hi) >> 1; if (batch[mid] < g + 1) lo = mid + 1; else hi = mid; }
        e = lo;
    }
    float sum = 0.0f;
    for (int i = s; i < e; ++i) sum += (float)h[(size_t)i * 128 + f];
    float cnt = (float)(e - s);
    float pooled = sum / fmaxf(cnt, 1.0f);

    __shared__ float l0[128], l1[128];
    l0[f] = pooled * lw[f * 2 + 0];
    l1[f] = pooled * lw[f * 2 + 1];
    __syncthreads();
    for (int sdt = 64; sdt > 0; sdt >>= 1) {
        if (f < sdt) { l0[f] += l0[f + sdt]; l1[f] += l1[f + sdt]; }
        __syncthreads();
    }
    if (f == 0) {
        float a = l0[0] + lb[0], b = l1[0] + lb[1];
        float m = fmaxf(a, b);
        float lse = m + logf(expf(a - m) + expf(b - m));
        out[g * 2 + 0] = a - lse;
        out[g * 2 + 1] = b - lse;
    }
}

// ---------------- forward-recurrence layer (layers 2-5), all-fp16 ----------------

template <int F, int FOUT>
static void run_layer_fwd(const _Float16* hh, _Float16* Zh, _Float16* houth,
                          const _Float16* Wt, const float* b, const int* rp,
                          const unsigned* ew, hipStream_t s) {
    constexpr int TPN = F / 4;
    int sp_grid = cdiv(N_NODES * TPN, 256);
    int mm_grid = cdiv(N_NODES, 64);
    const _Float16* nh_ = nullptr;
    // Z1 = L h
    spmm_fused<F, false, false, false><<<sp_grid, 256, 0, s>>>(
        rp, ew, hh, F, 1.f, nh_, 0, 0.f, nh_, 0, 0.f, nullptr, Zh + 0 * F, 4 * F);
    // Z2 = 2 L Z1 - h
    spmm_fused<F, true, false, false><<<sp_grid, 256, 0, s>>>(
        rp, ew, Zh + 0 * F, 4 * F, 2.f, hh, F, -1.f, nh_, 0, 0.f, nullptr, Zh + 1 * F, 4 * F);
    // Z3 = 2 L Z2 - Z1
    spmm_fused<F, true, false, false><<<sp_grid, 256, 0, s>>>(
        rp, ew, Zh + 1 * F, 4 * F, 2.f, Zh + 0 * F, 4 * F, -1.f, nh_, 0, 0.f, nullptr, Zh + 2 * F, 4 * F);
    // Z4 = 2 L Z3 - Z2
    spmm_fused<F, true, false, false><<<sp_grid, 256, 0, s>>>(
        rp, ew, Zh + 2 * F, 4 * F, 2.f, Zh + 1 * F, 4 * F, -1.f, nh_, 0, 0.f, nullptr, Zh + 3 * F, 4 * F);
    // out = relu([hh|Zh] @ W + b) in fp16
    mm_mfma<5 * F, F, FOUT, true, true><<<mm_grid, 256, 0, s>>>(hh, Zh, Wt, b, houth);
}

extern "C" void kernel_launch(void* const* d_in, const int* in_sizes, int n_in,
                              void* d_out, int out_size, void* d_ws, size_t ws_size,
                              hipStream_t stream) {
    const float* x = (const float*)d_in[0];
    const int* ei = (const int*)d_in[1];
    const int* batch = (const int*)d_in[2];
    const float* W1 = (const float*)d_in[3];
    const float* b1 = (const float*)d_in[4];
    const float* W2 = (const float*)d_in[5];
    const float* b2 = (const float*)d_in[6];
    const float* W3 = (const float*)d_in[7];
    const float* b3 = (const float*)d_in[8];
    const float* W4 = (const float*)d_in[9];
    const float* b4 = (const float*)d_in[10];
    const float* W5 = (const float*)d_in[11];
    const float* b5 = (const float*)d_in[12];
    const float* lin_w = (const float*)d_in[13];
    const float* lin_b = (const float*)d_in[14];
    const int* row = ei;
    const int* col = ei + N_EDGES;
    float* out = (float*)d_out;

    char* p = (char*)d_ws;
    auto alloc = [&](size_t bytes) {
        char* r = p;
        p += (bytes + 255) & ~(size_t)255;
        return r;
    };
    int* cnt = (int*)alloc((size_t)N_NODES * 4);
    int* rp = (int*)alloc((size_t)(N_NODES + 1) * 4);
    int* cursor = (int*)alloc((size_t)N_NODES * 4);
    int* bsum = (int*)alloc(256 * 4);
    int* gcur = (int*)alloc((size_t)NBUCK * 4);
    float* dinv = (float*)alloc((size_t)N_NODES * 4);
    unsigned* ew = (unsigned*)alloc((size_t)N_EDGES * 4);
    int2* stage = (int2*)alloc((size_t)N_EDGES * 8);
    _Float16* Zh = (_Float16*)alloc((size_t)N_NODES * 256 * 2);   // Uh [N,160] then Zh [N,256]
    _Float16* hAh = (_Float16*)alloc((size_t)N_NODES * 128 * 2);  // xh, h1h/h3h/h5h
    _Float16* hBh = (_Float16*)alloc((size_t)N_NODES * 128 * 2);  // B*h, h2h/h4h
    _Float16* wt1 = (_Float16*)alloc((size_t)160 * 128 * 2);
    _Float16* wt2 = (_Float16*)alloc((size_t)32 * 160 * 2);
    _Float16* wt3 = (_Float16*)alloc((size_t)64 * 160 * 2);
    _Float16* wt4 = (_Float16*)alloc((size_t)64 * 320 * 2);
    _Float16* wt5 = (_Float16*)alloc((size_t)128 * 320 * 2);

    const int NB = cdiv(N_NODES, 256);  // 196
    hipMemsetAsync(cnt, 0, (size_t)N_NODES * 4, stream);
    count_kernel<<<cdiv(N_EDGES, 256), 256, 0, stream>>>(row, cnt, N_EDGES);
    block_scan_kernel<<<NB, 256, 0, stream>>>(cnt, rp, bsum, N_NODES);
    scan_bsum_kernel<<<1, 256, 0, stream>>>(bsum, NB);
    add_off_kernel<<<NB, 256, 0, stream>>>(rp, bsum, N_NODES);
    dinv_cursor_kernel<<<cdiv(N_NODES, 256), 256, 0, stream>>>(cnt, rp, dinv, cursor, gcur,
                                                               N_NODES);
    bin_kernel<<<cdiv(N_EDGES, EPB_A), 256, 0, stream>>>(row, col, dinv, gcur, stage, N_EDGES);
    place_kernel<<<cdiv(N_EDGES, 256), 256, 0, stream>>>(stage, cursor, ew, N_EDGES);

    // fp16 prep (single fused kernel)
    const int CONV_TOT = N_NODES * 128 + 160 * 128 + 32 * 160 + 64 * 160 + 64 * 320 + 128 * 320;
    conv_all_kernel<<<cdiv(CONV_TOT, 256), 256, 0, stream>>>(x, W1, W2, W3, W4, W5, hAh, wt1,
                                                             wt2, wt3, wt4, wt5);

    // ---- Layer 1 via Clenshaw in 32-dim space (all-fp16) ----
    _Float16* Uh = Zh;  // [N,160]; dead before layer-2 Zh use
    const _Float16* nh_ = nullptr;
    mm_mfma<128, 128, 160, false, false><<<cdiv(N_NODES, 64), 256, 0, stream>>>(
        hAh, nh_, wt1, nullptr, Uh);
    _Float16* B3h = hBh;
    _Float16* B2h = hBh + (size_t)N_NODES * 32;
    _Float16* B1h = hBh + (size_t)N_NODES * 64;
    _Float16* h1h = hAh;  // xh dead after layer-1 mm
    int g32 = cdiv(N_NODES * 8, 256);
    // B3 = 2 L U4 + U3
    spmm_fused<32, true, false, false><<<g32, 256, 0, stream>>>(
        rp, ew, Uh + 128, 160, 2.f, Uh + 96, 160, 1.f, nh_, 0, 0.f, nullptr, B3h, 32);
    // B2 = 2 L B3 + U2 - U4
    spmm_fused<32, true, true, false><<<g32, 256, 0, stream>>>(
        rp, ew, B3h, 32, 2.f, Uh + 64, 160, 1.f, Uh + 128, 160, -1.f, nullptr, B2h, 32);
    // B1 = 2 L B2 + U1 - B3
    spmm_fused<32, true, true, false><<<g32, 256, 0, stream>>>(
        rp, ew, B2h, 32, 2.f, Uh + 32, 160, 1.f, B3h, 32, -1.f, nullptr, B1h, 32);
    // h1 = relu( L B1 + U0 - B2 + b1 )
    spmm_fused<32, true, true, true><<<g32, 256, 0, stream>>>(
        rp, ew, B1h, 32, 1.f, Uh + 0, 160, 1.f, B2h, 32, -1.f, b1, h1h, 32);

    // ---- Layers 2-5: fp16 recurrence + fp16 MFMA matmul ----
    run_layer_fwd<32, 32>(h1h, Zh, hBh, wt2, b2, rp, ew, stream);
    run_layer_fwd<32, 64>(hBh, Zh, hAh, wt3, b3, rp, ew, stream);
    run_layer_fwd<64, 64>(hAh, Zh, hBh, wt4, b4, rp, ew, stream);
    run_layer_fwd<64, 128>(hBh, Zh, hAh, wt5, b5, rp, ew, stream);

    pool_head_kernel<<<N_GRAPHS, 128, 0, stream>>>(hAh, batch, lin_w, lin_b, out);
}

// Round 14
// 590.901 us; speedup vs baseline: 1.0529x; 1.0529x over previous
//
#include <hip/hip_runtime.h>

#define N_NODES 50000
#define N_GRAPHS 500
#define N_EDGES 800000
#define BUCK_SHIFT 7
#define NBUCK 391   // cdiv(N_NODES, 128)
#define EPB_A 8192  // edges per bin block (32/thread)

static inline int cdiv(int a, int b) { return (a + b - 1) / b; }

typedef _Float16 half8v __attribute__((ext_vector_type(8)));
typedef _Float16 half4v __attribute__((ext_vector_type(4)));
typedef __attribute__((ext_vector_type(4))) float f32x4;

__device__ __forceinline__ _Float16 f2h(float f) { return (_Float16)f; }

// ---------------- CSR build ----------------

__global__ void count_kernel(const int* __restrict__ row, int* __restrict__ cnt, int e) {
    int t = blockIdx.x * blockDim.x + threadIdx.x;
    if (t < e) atomicAdd(&cnt[row[t]], 1);
}

__global__ void block_scan_kernel(const int* __restrict__ cnt, int* __restrict__ rp,
                                  int* __restrict__ bsum, int n) {
    __shared__ int buf[2][256];
    int t = threadIdx.x;
    int idx = blockIdx.x * 256 + t;
    int v = (idx < n) ? cnt[idx] : 0;
    buf[0][t] = v;
    __syncthreads();
    int s = 0;
#pragma unroll
    for (int off = 1; off < 256; off <<= 1) {
        int x = buf[s][t];
        if (t >= off) x += buf[s][t - off];
        buf[s ^ 1][t] = x;
        s ^= 1;
        __syncthreads();
    }
    if (idx < n) rp[idx] = buf[s][t] - v;  // exclusive within block
    if (t == 255) bsum[blockIdx.x] = buf[s][255];
}

__global__ void scan_bsum_kernel(int* __restrict__ bsum, int nb) {
    __shared__ int buf[2][256];
    int t = threadIdx.x;
    int v = (t < nb) ? bsum[t] : 0;
    buf[0][t] = v;
    __syncthreads();
    int s = 0;
#pragma unroll
    for (int off = 1; off < 256; off <<= 1) {
        int x = buf[s][t];
        if (t >= off) x += buf[s][t - off];
        buf[s ^ 1][t] = x;
        s ^= 1;
        __syncthreads();
    }
    if (t < nb) bsum[t] = buf[s][t] - v;  // exclusive
}

__global__ void add_off_kernel(int* __restrict__ rp, const int* __restrict__ bsum, int n) {
    int idx = blockIdx.x * 256 + threadIdx.x;
    if (idx < n) rp[idx] += bsum[idx >> 8];
    if (idx == 0) rp[n] = N_EDGES;
}

// cursor copy + dinv + per-bucket global cursors (gcur[b] = rp[b*128])
__global__ void dinv_cursor_kernel(const int* __restrict__ cnt, const int* __restrict__ rp,
                                   float* __restrict__ dinv, int* __restrict__ cursor,
                                   int* __restrict__ gcur, int n) {
    int t = blockIdx.x * blockDim.x + threadIdx.x;
    if (t < n) {
        int c = cnt[t];
        dinv[t] = (c > 0) ? rsqrtf((float)c) : 0.0f;
        cursor[t] = rp[t];
    }
    if (t < NBUCK) gcur[t] = rp[t << BUCK_SHIFT];
}

// Phase A: bin edges by row>>7 into bucket-contiguous staging.
__global__ __launch_bounds__(256) void bin_kernel(
    const int* __restrict__ row, const int* __restrict__ col,
    const float* __restrict__ dinv, int* __restrict__ gcur,
    int2* __restrict__ stage, int e) {
    __shared__ int lhist[NBUCK];
    __shared__ int lbase[NBUCK];
    int tid = threadIdx.x;
    int base = blockIdx.x * EPB_A;
    for (int b = tid; b < NBUCK; b += 256) lhist[b] = 0;
    __syncthreads();
#pragma unroll
    for (int u = 0; u < EPB_A / 256; ++u) {
        int e_ = base + u * 256 + tid;
        if (e_ < e) atomicAdd(&lhist[row[e_] >> BUCK_SHIFT], 1);
    }
    __syncthreads();
    for (int b = tid; b < NBUCK; b += 256) {
        int c = lhist[b];
        lbase[b] = c ? atomicAdd(&gcur[b], c) : 0;
        lhist[b] = 0;
    }
    __syncthreads();
#pragma unroll
    for (int u = 0; u < EPB_A / 256; ++u) {
        int e_ = base + u * 256 + tid;
        if (e_ < e) {
            int r = row[e_], c = col[e_];
            int b = r >> BUCK_SHIFT;
            int pos = lbase[b] + atomicAdd(&lhist[b], 1);
            float w = -dinv[r] * dinv[c];
            unsigned short wb = __builtin_bit_cast(unsigned short, (_Float16)w);
            stage[pos] = make_int2(r, (int)(((unsigned)c << 16) | (unsigned)wb));
        }
    }
}

// Phase B: place within bucket (destination region ~8KB -> L2-hot).
__global__ void place_kernel(const int2* __restrict__ stage, int* __restrict__ cursor,
                             unsigned* __restrict__ ew, int e) {
    int t = blockIdx.x * blockDim.x + threadIdx.x;
    if (t < e) {
        int2 s = stage[t];
        int pos = atomicAdd(&cursor[s.x], 1);
        ew[pos] = (unsigned)s.y;
    }
}

// ---------------- fused fp16 conversions (single kernel) ----------------

__global__ void conv_all_kernel(const float* __restrict__ x, const float* __restrict__ W1,
                                const float* __restrict__ W2, const float* __restrict__ W3,
                                const float* __restrict__ W4, const float* __restrict__ W5,
                                _Float16* __restrict__ xh, _Float16* __restrict__ wt1,
                                _Float16* __restrict__ wt2, _Float16* __restrict__ wt3,
                                _Float16* __restrict__ wt4, _Float16* __restrict__ wt5) {
    int t = blockIdx.x * blockDim.x + threadIdx.x;
    const int NX = N_NODES * 128;
    if (t < NX) {
        int r = t >> 7, c = t & 127;
        xh[t] = (c < 116) ? f2h(x[(size_t)r * 116 + c]) : (_Float16)0.f;
        return;
    }
    t -= NX;
    if (t < 160 * 128) {  // wt1[c][k] = W1[c/32][k][c%32], zero-pad k>=116
        int c = t >> 7, k = t & 127;
        wt1[t] = (k < 116) ? f2h(W1[(c >> 5) * (116 * 32) + k * 32 + (c & 31)]) : (_Float16)0.f;
        return;
    }
    t -= 160 * 128;
    if (t < 32 * 160) { int c = t / 160, k = t % 160; wt2[t] = f2h(W2[(size_t)k * 32 + c]); return; }
    t -= 32 * 160;
    if (t < 64 * 160) { int c = t / 160, k = t % 160; wt3[t] = f2h(W3[(size_t)k * 64 + c]); return; }
    t -= 64 * 160;
    if (t < 64 * 320) { int c = t / 320, k = t % 320; wt4[t] = f2h(W4[(size_t)k * 64 + c]); return; }
    t -= 64 * 320;
    if (t < 128 * 320) { int c = t / 320, k = t % 320; wt5[t] = f2h(W5[(size_t)k * 128 + c]); }
}

// ---------------- fused SpMM (all-fp16, 16B gathers: 8 features/thread) ----------------
// TPN = F/8 threads per node; each gather is one half8v (16B) -> half the L2
// line-requests per edge vs the 8B mapping (measured bound: request slots).

template <int F, bool HAS_A, bool HAS_B, bool RELU>
__global__ __launch_bounds__(256) void spmm_fused(
    const int* __restrict__ rp, const unsigned* __restrict__ ew,
    const _Float16* __restrict__ src, int ld_s, float alpha,
    const _Float16* __restrict__ A, int ldA, float cA,
    const _Float16* __restrict__ B, int ldB, float cB,
    const float* __restrict__ bias, _Float16* __restrict__ outh, int ldO) {
    constexpr int TPN = F / 8;
    int t = blockIdx.x * blockDim.x + threadIdx.x;
    if (t >= N_NODES * TPN) return;
    int node = t / TPN;
    int fo = (t % TPN) * 8;
    const _Float16* sf = src + fo;
    int e0 = rp[node], e1 = rp[node + 1];
    float a[8];
#pragma unroll
    for (int q = 0; q < 8; ++q) a[q] = 0.f;
    int j = e0;
    for (; j + 7 < e1; j += 8) {
        unsigned e_[8];
#pragma unroll
        for (int u = 0; u < 8; ++u) e_[u] = ew[j + u];
        half8v v_[8];
#pragma unroll
        for (int u = 0; u < 8; ++u) v_[u] = *(const half8v*)(sf + (size_t)(e_[u] >> 16) * ld_s);
#pragma unroll
        for (int u = 0; u < 8; ++u) {
            float w = (float)__builtin_bit_cast(_Float16, (unsigned short)e_[u]);
#pragma unroll
            for (int q = 0; q < 8; ++q) a[q] += w * (float)v_[u][q];
        }
    }
    for (; j + 3 < e1; j += 4) {
        unsigned e_[4];
#pragma unroll
        for (int u = 0; u < 4; ++u) e_[u] = ew[j + u];
        half8v v_[4];
#pragma unroll
        for (int u = 0; u < 4; ++u) v_[u] = *(const half8v*)(sf + (size_t)(e_[u] >> 16) * ld_s);
#pragma unroll
        for (int u = 0; u < 4; ++u) {
            float w = (float)__builtin_bit_cast(_Float16, (unsigned short)e_[u]);
#pragma unroll
            for (int q = 0; q < 8; ++q) a[q] += w * (float)v_[u][q];
        }
    }
    for (; j < e1; ++j) {
        unsigned ea = ew[j];
        float w0 = (float)__builtin_bit_cast(_Float16, (unsigned short)ea);
        half8v v0 = *(const half8v*)(sf + (size_t)(ea >> 16) * ld_s);
#pragma unroll
        for (int q = 0; q < 8; ++q) a[q] += w0 * (float)v0[q];
    }
    float r[8];
#pragma unroll
    for (int q = 0; q < 8; ++q) r[q] = alpha * a[q];
    if (HAS_A) {
        half8v a8 = *(const half8v*)(A + (size_t)node * ldA + fo);
#pragma unroll
        for (int q = 0; q < 8; ++q) r[q] += cA * (float)a8[q];
    }
    if (HAS_B) {
        half8v b8 = *(const half8v*)(B + (size_t)node * ldB + fo);
#pragma unroll
        for (int q = 0; q < 8; ++q) r[q] += cB * (float)b8[q];
    }
    if (RELU) {
#pragma unroll
        for (int q = 0; q < 8; ++q) r[q] = fmaxf(r[q] + bias[fo + q], 0.f);
    }
    half8v o8;
#pragma unroll
    for (int q = 0; q < 8; ++q) o8[q] = f2h(r[q]);
    *(half8v*)(outh + (size_t)node * ldO + fo) = o8;
}

// ---------------- MFMA matmul (fp16, W staged in LDS) ----------------
// C/D: col = lane&15, row = (lane>>4)*4 + reg  [verified layout].

template <int KB, int F0, int FOUT, bool DUAL, bool RELU>
__global__ __launch_bounds__(256) void mm_mfma(const _Float16* __restrict__ A0h,
                                               const _Float16* __restrict__ A1h,
                                               const _Float16* __restrict__ Wt,
                                               const float* __restrict__ bias,
                                               _Float16* __restrict__ outh) {
    constexpr int NT = FOUT / 16;
    constexpr int LD1 = (KB - F0) > 0 ? (KB - F0) : 1;
    constexpr int KC = (KB > 160) ? 160 : KB;
    constexpr int NCH = KB / KC;
    constexpr int LDW = KC + 8;
    __shared__ _Float16 lw[FOUT][LDW];

    int tid = threadIdx.x;
    int l = tid & 63;
    int w = tid >> 6;
    int row0 = blockIdx.x * 64 + w * 16;
    int r15 = l & 15;
    int kg = l >> 4;
    int rr = row0 + r15;
    if (rr > N_NODES - 1) rr = N_NODES - 1;  // clamp; stores are guarded

    f32x4 acc[NT];
#pragma unroll
    for (int ct = 0; ct < NT; ++ct) acc[ct] = (f32x4){0.f, 0.f, 0.f, 0.f};

#pragma unroll
    for (int ch = 0; ch < NCH; ++ch) {
        constexpr int C8 = KC / 8;
        int c0 = ch * KC;
        for (int idx = tid; idx < FOUT * C8; idx += 256) {
            int r = idx / C8, c8 = idx - r * C8;
            *(half8v*)&lw[r][c8 * 8] = *(const half8v*)(Wt + (size_t)r * KB + c0 + c8 * 8);
        }
        __syncthreads();
#pragma unroll
        for (int k0 = 0; k0 < KC; k0 += 32) {
            int gc = c0 + k0;
            int kl = gc + kg * 8;
            const _Float16* ap;
            if (!DUAL || gc < F0)
                ap = A0h + (size_t)rr * F0 + kl;
            else
                ap = A1h + (size_t)rr * LD1 + (kl - F0);
            half8v af = *(const half8v*)ap;
#pragma unroll
            for (int ct = 0; ct < NT; ++ct) {
                half8v bf = *(const half8v*)&lw[ct * 16 + r15][k0 + kg * 8];
                acc[ct] = __builtin_amdgcn_mfma_f32_16x16x32_f16(af, bf, acc[ct], 0, 0, 0);
            }
        }
        __syncthreads();
    }

    int orow = row0 + kg * 4;
#pragma unroll
    for (int ct = 0; ct < NT; ++ct) {
        int col = ct * 16 + r15;
        float bv = RELU ? bias[col] : 0.f;
#pragma unroll
        for (int i = 0; i < 4; ++i) {
            int rw = orow + i;
            if (rw < N_NODES) {
                float v = acc[ct][i];
                if (RELU) v = fmaxf(v + bv, 0.f);
                outh[(size_t)rw * FOUT + col] = f2h(v);
            }
        }
    }
}

// ---------------- pooling + linear + log_softmax (parallel rows) ----------------
// 256 thr = 16 row-groups x 16 feature-lanes (half8v). LDS partial reduce.

__global__ __launch_bounds__(256) void pool_head_kernel(
    const _Float16* __restrict__ h, const int* __restrict__ batch,
    const float* __restrict__ lw, const float* __restrict__ lb, float* __restrict__ out) {
    int g = blockIdx.x;
    int tid = threadIdx.x;
    int s, e;
    {
        int lo = 0, hi = N_NODES;
        while (lo < hi) { int mid = (lo + hi) >> 1; if (batch[mid] < g) lo = mid + 1; else hi = mid; }
        s = lo;
        hi = N_NODES;
        while (lo < hi) { int mid = (lo + hi) >> 1; if (batch[mid] < g + 1) lo = mid + 1; else hi = mid; }
        e = lo;
    }
    int rg = tid >> 4;        // row group 0..15
    int fo = (tid & 15) * 8;  // feature offset
    float a[8];
#pragma unroll
    for (int q = 0; q < 8; ++q) a[q] = 0.f;
    for (int i = s + rg; i < e; i += 16) {
        half8v v = *(const half8v*)(h + (size_t)i * 128 + fo);
#pragma unroll
        for (int q = 0; q < 8; ++q) a[q] += (float)v[q];
    }
    __shared__ float part[16][128];
#pragma unroll
    for (int q = 0; q < 8; ++q) part[rg][fo + q] = a[q];
    __syncthreads();
    __shared__ float l0[128], l1[128];
    if (tid < 128) {
        float sum = 0.f;
#pragma unroll
        for (int r2 = 0; r2 < 16; ++r2) sum += part[r2][tid];
        float cnt = (float)(e - s);
        float pooled = sum / fmaxf(cnt, 1.0f);
        l0[tid] = pooled * lw[tid * 2 + 0];
        l1[tid] = pooled * lw[tid * 2 + 1];
    }
    __syncthreads();
    for (int sdt = 64; sdt > 0; sdt >>= 1) {
        if (tid < sdt) { l0[tid] += l0[tid + sdt]; l1[tid] += l1[tid + sdt]; }
        __syncthreads();
    }
    if (tid == 0) {
        float av = l0[0] + lb[0], bv = l1[0] + lb[1];
        float m = fmaxf(av, bv);
        float lse = m + logf(expf(av - m) + expf(bv - m));
        out[g * 2 + 0] = av - lse;
        out[g * 2 + 1] = bv - lse;
    }
}

// ---------------- forward-recurrence layer (layers 2-5), all-fp16 ----------------

template <int F, int FOUT>
static void run_layer_fwd(const _Float16* hh, _Float16* Zh, _Float16* houth,
                          const _Float16* Wt, const float* b, const int* rp,
                          const unsigned* ew, hipStream_t s) {
    constexpr int TPN = F / 8;
    int sp_grid = cdiv(N_NODES * TPN, 256);
    int mm_grid = cdiv(N_NODES, 64);
    const _Float16* nh_ = nullptr;
    // Z1 = L h
    spmm_fused<F, false, false, false><<<sp_grid, 256, 0, s>>>(
        rp, ew, hh, F, 1.f, nh_, 0, 0.f, nh_, 0, 0.f, nullptr, Zh + 0 * F, 4 * F);
    // Z2 = 2 L Z1 - h
    spmm_fused<F, true, false, false><<<sp_grid, 256, 0, s>>>(
        rp, ew, Zh + 0 * F, 4 * F, 2.f, hh, F, -1.f, nh_, 0, 0.f, nullptr, Zh + 1 * F, 4 * F);
    // Z3 = 2 L Z2 - Z1
    spmm_fused<F, true, false, false><<<sp_grid, 256, 0, s>>>(
        rp, ew, Zh + 1 * F, 4 * F, 2.f, Zh + 0 * F, 4 * F, -1.f, nh_, 0, 0.f, nullptr, Zh + 2 * F, 4 * F);
    // Z4 = 2 L Z3 - Z2
    spmm_fused<F, true, false, false><<<sp_grid, 256, 0, s>>>(
        rp, ew, Zh + 2 * F, 4 * F, 2.f, Zh + 1 * F, 4 * F, -1.f, nh_, 0, 0.f, nullptr, Zh + 3 * F, 4 * F);
    // out = relu([hh|Zh] @ W + b) in fp16
    mm_mfma<5 * F, F, FOUT, true, true><<<mm_grid, 256, 0, s>>>(hh, Zh, Wt, b, houth);
}

extern "C" void kernel_launch(void* const* d_in, const int* in_sizes, int n_in,
                              void* d_out, int out_size, void* d_ws, size_t ws_size,
                              hipStream_t stream) {
    const float* x = (const float*)d_in[0];
    const int* ei = (const int*)d_in[1];
    const int* batch = (const int*)d_in[2];
    const float* W1 = (const float*)d_in[3];
    const float* b1 = (const float*)d_in[4];
    const float* W2 = (const float*)d_in[5];
    const float* b2 = (const float*)d_in[6];
    const float* W3 = (const float*)d_in[7];
    const float* b3 = (const float*)d_in[8];
    const float* W4 = (const float*)d_in[9];
    const float* b4 = (const float*)d_in[10];
    const float* W5 = (const float*)d_in[11];
    const float* b5 = (const float*)d_in[12];
    const float* lin_w = (const float*)d_in[13];
    const float* lin_b = (const float*)d_in[14];
    const int* row = ei;
    const int* col = ei + N_EDGES;
    float* out = (float*)d_out;

    char* p = (char*)d_ws;
    auto alloc = [&](size_t bytes) {
        char* r = p;
        p += (bytes + 255) & ~(size_t)255;
        return r;
    };
    int* cnt = (int*)alloc((size_t)N_NODES * 4);
    int* rp = (int*)alloc((size_t)(N_NODES + 1) * 4);
    int* cursor = (int*)alloc((size_t)N_NODES * 4);
    int* bsum = (int*)alloc(256 * 4);
    int* gcur = (int*)alloc((size_t)NBUCK * 4);
    float* dinv = (float*)alloc((size_t)N_NODES * 4);
    unsigned* ew = (unsigned*)alloc((size_t)N_EDGES * 4);
    int2* stage = (int2*)alloc((size_t)N_EDGES * 8);
    _Float16* Zh = (_Float16*)alloc((size_t)N_NODES * 256 * 2);   // Uh [N,160] then Zh [N,256]
    _Float16* hAh = (_Float16*)alloc((size_t)N_NODES * 128 * 2);  // xh, h1h/h3h/h5h
    _Float16* hBh = (_Float16*)alloc((size_t)N_NODES * 128 * 2);  // B*h, h2h/h4h
    _Float16* wt1 = (_Float16*)alloc((size_t)160 * 128 * 2);
    _Float16* wt2 = (_Float16*)alloc((size_t)32 * 160 * 2);
    _Float16* wt3 = (_Float16*)alloc((size_t)64 * 160 * 2);
    _Float16* wt4 = (_Float16*)alloc((size_t)64 * 320 * 2);
    _Float16* wt5 = (_Float16*)alloc((size_t)128 * 320 * 2);

    const int NB = cdiv(N_NODES, 256);  // 196
    hipMemsetAsync(cnt, 0, (size_t)N_NODES * 4, stream);
    count_kernel<<<cdiv(N_EDGES, 256), 256, 0, stream>>>(row, cnt, N_EDGES);
    block_scan_kernel<<<NB, 256, 0, stream>>>(cnt, rp, bsum, N_NODES);
    scan_bsum_kernel<<<1, 256, 0, stream>>>(bsum, NB);
    add_off_kernel<<<NB, 256, 0, stream>>>(rp, bsum, N_NODES);
    dinv_cursor_kernel<<<cdiv(N_NODES, 256), 256, 0, stream>>>(cnt, rp, dinv, cursor, gcur,
                                                               N_NODES);
    bin_kernel<<<cdiv(N_EDGES, EPB_A), 256, 0, stream>>>(row, col, dinv, gcur, stage, N_EDGES);
    place_kernel<<<cdiv(N_EDGES, 256), 256, 0, stream>>>(stage, cursor, ew, N_EDGES);

    // fp16 prep (single fused kernel)
    const int CONV_TOT = N_NODES * 128 + 160 * 128 + 32 * 160 + 64 * 160 + 64 * 320 + 128 * 320;
    conv_all_kernel<<<cdiv(CONV_TOT, 256), 256, 0, stream>>>(x, W1, W2, W3, W4, W5, hAh, wt1,
                                                             wt2, wt3, wt4, wt5);

    // ---- Layer 1 via Clenshaw in 32-dim space (all-fp16) ----
    _Float16* Uh = Zh;  // [N,160]; dead before layer-2 Zh use
    const _Float16* nh_ = nullptr;
    mm_mfma<128, 128, 160, false, false><<<cdiv(N_NODES, 64), 256, 0, stream>>>(
        hAh, nh_, wt1, nullptr, Uh);
    _Float16* B3h = hBh;
    _Float16* B2h = hBh + (size_t)N_NODES * 32;
    _Float16* B1h = hBh + (size_t)N_NODES * 64;
    _Float16* h1h = hAh;  // xh dead after layer-1 mm
    int g32 = cdiv(N_NODES * 4, 256);
    // B3 = 2 L U4 + U3
    spmm_fused<32, true, false, false><<<g32, 256, 0, stream>>>(
        rp, ew, Uh + 128, 160, 2.f, Uh + 96, 160, 1.f, nh_, 0, 0.f, nullptr, B3h, 32);
    // B2 = 2 L B3 + U2 - U4
    spmm_fused<32, true, true, false><<<g32, 256, 0, stream>>>(
        rp, ew, B3h, 32, 2.f, Uh + 64, 160, 1.f, Uh + 128, 160, -1.f, nullptr, B2h, 32);
    // B1 = 2 L B2 + U1 - B3
    spmm_fused<32, true, true, false><<<g32, 256, 0, stream>>>(
        rp, ew, B2h, 32, 2.f, Uh + 32, 160, 1.f, B3h, 32, -1.f, nullptr, B1h, 32);
    // h1 = relu( L B1 + U0 - B2 + b1 )
    spmm_fused<32, true, true, true><<<g32, 256, 0, stream>>>(
        rp, ew, B1h, 32, 1.f, Uh + 0, 160, 1.f, B2h, 32, -1.f, b1, h1h, 32);

    // ---- Layers 2-5: fp16 recurrence + fp16 MFMA matmul ----
    run_layer_fwd<32, 32>(h1h, Zh, hBh, wt2, b2, rp, ew, stream);
    run_layer_fwd<32, 64>(hBh, Zh, hAh, wt3, b3, rp, ew, stream);
    run_layer_fwd<64, 64>(hAh, Zh, hBh, wt4, b4, rp, ew, stream);
    run_layer_fwd<64, 128>(hBh, Zh, hAh, wt5, b5, rp, ew, stream);

    pool_head_kernel<<<N_GRAPHS, 256, 0, stream>>>(hAh, batch, lin_w, lin_b, out);
}